// Round 6
// baseline (4461.535 us; speedup 1.0000x reference)
//
#include <hip/hip_runtime.h>
#include <math.h>

typedef unsigned char u8;

#define KK 16
#define TT 40
#define BB 16
#define NN 32
#define BN 512
#define KBN 8192

// ws float offsets — total 5,033,984 floats = 20,135,936 bytes (~20.1 MB)
#define OFF_FM   0u          // 16*80*80*32 = 3276800   fm (b,oh,ow,oc)
#define OFF_C1   3276800u    // 16*16*80*80 = 1638400
#define OFF_W2T  4915200u    // 12800   conv2 W as (ic,kh,kw,oc)
#define OFF_WT9  4928000u    // 20736   wt9[kk2][c][g] g in {r,z,n}: gate-aligned GRU weights
#define OFF_WH3  4948736u    // 2304    wh3[kk2s][c] = whh[(96+c)*48+kk2s]  (n-gate h weights)
#define OFF_WGT  4951040u    // 82944   wgt[bin][hh][cc] = scfw[cc][bin*48+hh]

__global__ __launch_bounds__(256) void k_prep(const float* conv2_w, const float* scfw,
                                              const float* wih, const float* whh,
                                              float* w2t, float* wt9g, float* wh3g, float* wgt_g){
  int idx = blockIdx.x*256 + threadIdx.x;
  if (idx < 12800) {
    int oc = idx & 31; int rest = idx >> 5;        // rest = ic*25+kh*5+kw
    w2t[idx] = conv2_w[oc*400 + rest];
  }
  int i2 = idx - 12800;
  if (i2 >= 0 && i2 < 20736) {                     // wt9[kk2][c][g], o = g*48+c
    int kk2 = i2 / 144, rem = i2 % 144;
    int c = rem / 3, g = rem % 3;
    int o = g*48 + c;
    wt9g[i2] = (kk2 < 96) ? wih[o*96 + kk2] : whh[o*48 + (kk2 - 96)];
  }
  int i3 = idx - 33536;
  if (i3 >= 0 && i3 < 2304) {                      // wh3[kk2s][c]
    int kk2s = i3 / 48, c = i3 % 48;
    wh3g[i3] = whh[(96 + c)*48 + kk2s];
  }
  int i4 = idx - 35840;
  if (i4 >= 0 && i4 < 82944) {                     // wgt[bin][hh][cc]
    int bin = i4 / 2304, r2 = i4 % 2304;
    int hh = r2 / 48, cc = r2 % 48;
    wgt_g[i4] = scfw[cc*1728 + bin*48 + hh];
  }
}

__global__ __launch_bounds__(256) void k_conv1(const float* img, const float* w1, const float* b1, float* c1){
  int idx = blockIdx.x*256 + threadIdx.x;          // (b,oc,oh,ow) ow fastest
  int ow = idx % 80, t1 = idx / 80;
  int oh = t1 % 80, t2 = t1 / 80;
  int oc = t2 % 16, b = t2 / 16;
  float acc = b1[oc];
  for (int ic = 0; ic < 4; ++ic)
    for (int kh = 0; kh < 5; ++kh) {
      int ih = oh*2 - 2 + kh;
      if (ih < 0 || ih >= 160) continue;
      const float* ip = img + ((b*4 + ic)*160 + ih)*160;
      const float* wp = w1 + ((oc*4 + ic)*5 + kh)*5;
      #pragma unroll
      for (int kw = 0; kw < 5; ++kw) {
        int iw = ow*2 - 2 + kw;
        if (iw >= 0 && iw < 160) acc += ip[iw] * wp[kw];
      }
    }
  c1[idx] = fmaxf(acc, 0.f);
}

__global__ __launch_bounds__(256) void k_conv2(const float* c1, const float* w2t, const float* b2, float* fm){
  int idx = blockIdx.x*256 + threadIdx.x;          // (b,oh,owg,oc) oc fastest, 4 ow per thread
  int oc = idx & 31;
  int t1 = idx >> 5;
  int owg = t1 % 20; int t2 = t1 / 20;
  int oh = t2 % 80; int b = t2 / 80;
  int ow0 = owg*4;
  float acc0=b2[oc],acc1=b2[oc],acc2=b2[oc],acc3=b2[oc];
  for (int ic = 0; ic < 16; ++ic)
    for (int kh = 0; kh < 5; ++kh) {
      int ih = oh - 2 + kh;
      if (ih < 0 || ih >= 80) continue;
      const float* ip = c1 + ((b*16 + ic)*80 + ih)*80;
      float cv[8];
      #pragma unroll
      for (int q = 0; q < 8; ++q) {
        int iw = ow0 - 2 + q;
        cv[q] = (iw >= 0 && iw < 80) ? ip[iw] : 0.f;
      }
      const float* wp = w2t + (ic*25 + kh*5)*32 + oc;
      #pragma unroll
      for (int kw = 0; kw < 5; ++kw) {
        float wv = wp[kw*32];
        acc0 += cv[kw]   * wv;
        acc1 += cv[kw+1] * wv;
        acc2 += cv[kw+2] * wv;
        acc3 += cv[kw+3] * wv;
      }
    }
  float* op = fm + ((b*80 + oh)*80 + ow0)*32 + oc;
  op[0]  = fmaxf(acc0, 0.f);
  op[32] = fmaxf(acc1, 0.f);
  op[64] = fmaxf(acc2, 0.f);
  op[96] = fmaxf(acc3, 0.f);
}

// Persistent recurrence: one block per (kk,bb) panel, all 40 timesteps in-kernel.
// X rows 0-31: base panel replica (k=0, self-contained evolution, identical in
// every block sharing bb). X rows 32-63: own panel (k=kk). No cross-block deps.
__global__ __launch_bounds__(256) void k_seq(
    const float* __restrict__ y_path, const float* __restrict__ cur_loc,
    const float* __restrict__ fm, const float* __restrict__ wgt,
    const float* __restrict__ wt9g,
    const float* __restrict__ vw, const float* __restrict__ vb2,
    const float* __restrict__ scfb, const float* __restrict__ bih,
    const float* __restrict__ bhh, const float* __restrict__ scw,
    const float* __restrict__ scb, const float* __restrict__ dyw,
    const float* __restrict__ dyb, const float* __restrict__ hx,
    float* __restrict__ out)
{
  __align__(16) __shared__ float wts[23040];   // [0,20736) wt9, [20736,23040) wh3
  __shared__ float X[64][148];                 // [0..95]=x, [96..143]=h
  __shared__ float PX[2][32], PY[2][32];       // [0]=base(k=0), [1]=own(k=kk)
  __shared__ u8 BINM[2][32][32];
  __shared__ int PLE[2048];                    // (bin<<16)|(jf<<8)|q
  __shared__ float PWL[2048];
  __shared__ float SROW[32];
  __shared__ float SV[432];                    // 0:vw 32:vb 48:scfb 96:bih 240:bhh 384:scw
  __shared__ int lcnt;

  int tid = threadIdx.x;
  int kk = blockIdx.x >> 4;
  int bb = blockIdx.x & 15;

  // ---- one-time staging
  {
    const float4* src = reinterpret_cast<const float4*>(wt9g);  // wt9g+wh3g contiguous
    float4* dst = reinterpret_cast<float4*>(wts);
    for (int i = tid; i < 5760; i += 256) dst[i] = src[i];
  }
  for (int i = tid; i < 432; i += 256) {
    float v;
    if (i < 32) v = vw[i];
    else if (i < 48) v = vb2[i-32];
    else if (i < 96) v = scfb[i-48];
    else if (i < 240) v = bih[i-96];
    else if (i < 384) v = bhh[i-240];
    else v = scw[i-384];
    SV[i] = v;
  }
  for (int i = tid; i < 64*48; i += 256) {
    int r = i/48, c = i%48;
    X[r][96+c] = hx[(bb*32 + (r & 31))*48 + c];
  }
  if (tid < 32) SROW[tid] = 0.f;

  int tx = tid & 15, ty = tid >> 4;
  int r0 = ty*4;
  float sacc[4] = {0.f, 0.f, 0.f, 0.f};

  for (int t = 0; t < TT; ++t) {
    __syncthreads();
    // ---- positions for both panels
    if (tid < 64) {
      int p = tid >> 5, j = tid & 31;
      int kid = p ? kk : 0;
      PX[p][j] = y_path[((kid*TT + t)*BN + bb*32 + j)*2];
      PY[p][j] = y_path[((kid*TT + t)*BN + bb*32 + j)*2 + 1];
    }
    if (tid == 0) lcnt = 0;
    __syncthreads();

    // ---- pair bins for both panels (c = other(q) - agent(j))
    for (int it2 = 0; it2 < 8; ++it2) {
      int idx = tid + it2*256;               // 2*32*32
      int p = idx >> 10, rem = idx & 1023;
      int j = rem >> 5, q = rem & 31;
      float dx = PX[p][q] - PX[p][j], dy = PY[p][q] - PY[p][j];
      float dist = sqrtf(dx*dx + dy*dy);
      int bin = 255;
      if (q != j && dist >= 0.5f && dist <= 4.0f) {
        float ct = fminf(1.f, fmaxf(-1.f, dx / dist));
        float costh = acosf(ct);
        float theta = (dy < -0.01f) ? (6.28318530717958647692f - costh) : costh;
        int ub = (int)((dist - 0.5f) / 0.58333331346511840820f);
        ub = min(max(ub, 0), 5);
        int vb = (int)(theta / 1.04719758033752441406f);
        vb = min(max(vb, 0), 5);
        bin = ub*6 + vb;
      }
      BINM[p][j][q] = (u8)bin;
    }
    __syncthreads();

    // ---- compact pair list + assemble X cols 0..95
    for (int it2 = 0; it2 < 8; ++it2) {
      int idx = tid + it2*256;
      int p = idx >> 10, rem = idx & 1023;
      int j = rem >> 5, q = rem & 31;
      int bq = BINM[p][j][q];
      if (bq != 255) {
        int cnt2 = 0;
        #pragma unroll
        for (int q2 = 0; q2 < 32; ++q2) cnt2 += (BINM[p][j][q2] == bq) ? 1 : 0;
        int idx2 = atomicAdd(&lcnt, 1);
        PLE[idx2] = (bq << 16) | ((p*32 + j) << 8) | q;
        PWL[idx2] = 1.0f / (float)cnt2;
      }
    }
    for (int it2 = 0; it2 < 24; ++it2) {
      int task = tid + it2*256;              // 64*96
      int r = task / 96, c = task % 96;
      int p = r >> 5, j = r & 31;
      float val;
      if (c < 32) {
        int u = min(max(40 - (int)PY[p][j], 0), 79);
        int v = min(max((int)PX[p][j], 0), 79);
        val = fm[((bb*80 + u)*80 + v)*32 + c];
      } else if (c < 48) {
        int o = c - 32;
        int rr = bb*32 + j;
        float qx, qy;
        if (t == 0) { qx = cur_loc[rr*2]; qy = cur_loc[rr*2 + 1]; }
        else {
          int kid = p ? kk : 0;
          qx = y_path[((kid*TT + t - 1)*BN + rr)*2];
          qy = y_path[((kid*TT + t - 1)*BN + rr)*2 + 1];
        }
        float vx = (PX[p][j] - qx)*10.f, vy = (PY[p][j] - qy)*10.f;
        val = vx*SV[o*2] + vy*SV[o*2 + 1] + SV[32 + o];
      } else {
        val = SV[c];                          // scfb[c-48]
      }
      X[r][c] = val;
    }
    __syncthreads();

    // ---- sparse social pooling: X[jf][48+lane] += w * (Hbase[q] @ Wblock[bin])
    {
      int P = lcnt;
      int wid = tid >> 6, lane = tid & 63;
      if (lane < 48) {
        for (int p2 = wid; p2 < P; p2 += 4) {
          int e = PLE[p2];
          int bin = e >> 16, jf = (e >> 8) & 255, q = e & 255;
          float wv = PWL[p2];
          const float* wp = wgt + bin*2304 + lane;
          float acc = 0.f;
          #pragma unroll
          for (int hh = 0; hh < 48; ++hh) acc += X[q][96+hh] * wp[hh*48];
          atomicAdd(&X[jf][48 + lane], wv * acc);
        }
      }
    }
    __syncthreads();

    // ---- GRU GEMM: 64 rows, thread owns 4 rows x cols {3tx,3tx+1,3tx+2} all gates
    float a9[4][9], a3[4][3];
    #pragma unroll
    for (int ri = 0; ri < 4; ++ri) {
      #pragma unroll
      for (int m = 0; m < 9; ++m) a9[ri][m] = 0.f;
      #pragma unroll
      for (int m = 0; m < 3; ++m) a3[ri][m] = 0.f;
    }
    for (int k2 = 0; k2 < 144; ++k2) {
      float x0 = X[r0][k2], x1 = X[r0+1][k2], x2 = X[r0+2][k2], x3 = X[r0+3][k2];
      const float* wr = wts + k2*144 + 9*tx;
      #pragma unroll
      for (int m = 0; m < 9; ++m) {
        float wvm = wr[m];
        a9[0][m] += x0*wvm;
        a9[1][m] += x1*wvm;
        a9[2][m] += x2*wvm;
        a9[3][m] += x3*wvm;
      }
    }
    for (int k2 = 0; k2 < 48; ++k2) {
      float x0 = X[r0][96+k2], x1 = X[r0+1][96+k2], x2 = X[r0+2][96+k2], x3 = X[r0+3][96+k2];
      const float* wr = wts + 20736 + k2*48 + 3*tx;
      #pragma unroll
      for (int m = 0; m < 3; ++m) {
        float wvm = wr[m];
        a3[0][m] += x0*wvm;
        a3[1][m] += x1*wvm;
        a3[2][m] += x2*wvm;
        a3[3][m] += x3*wvm;
      }
    }
    float hn[4][3];
    #pragma unroll
    for (int ri = 0; ri < 4; ++ri)
      #pragma unroll
      for (int c3 = 0; c3 < 3; ++c3) {
        int c = 3*tx + c3;
        float gR = a9[ri][3*c3+0] + SV[96+c]     + SV[240+c];
        float gZ = a9[ri][3*c3+1] + SV[96+48+c]  + SV[240+48+c];
        float gN = a9[ri][3*c3+2] + SV[96+96+c]  + SV[240+96+c];
        float g3 = a3[ri][c3] + SV[240+96+c];
        float rg = 1.f/(1.f + expf(-gR));
        float zg = 1.f/(1.f + expf(-gZ));
        float nn2 = tanhf(gN + (rg - 1.f)*g3);
        float hold = X[r0+ri][96+c];
        hn[ri][c3] = (1.f - zg)*nn2 + zg*hold;
      }
    __syncthreads();   // all reads of old h complete before overwrite

    // ---- commit h + score partial (own rows only, register-accumulated)
    #pragma unroll
    for (int ri = 0; ri < 4; ++ri) {
      float sp = 0.f;
      #pragma unroll
      for (int c3 = 0; c3 < 3; ++c3) {
        int c = 3*tx + c3;
        X[r0+ri][96+c] = hn[ri][c3];
        sp += hn[ri][c3]*SV[384+c];
      }
      sacc[ri] += sp;
    }
  }
  // flush per-thread score partials (own panel = rows 32-63 → ty >= 8)
  if (ty >= 8) {
    #pragma unroll
    for (int ri = 0; ri < 4; ++ri) atomicAdd(&SROW[r0 + ri - 32], sacc[ri]);
  }
  __syncthreads();

  // ---- epilogue: score + delta_y from own rows (32-63)
  if (tid < 32) out[KBN*80 + kk*512 + bb*32 + tid] = SROW[tid] + (float)TT * scb[0];
  for (int it2 = 0; it2 < 10; ++it2) {
    int task = tid + it2*256;                // 32*80
    int r = task / 80, c = task % 80;
    float acc = dyb[c];
    #pragma unroll
    for (int i = 0; i < 48; ++i) acc += X[32+r][96+i] * dyw[c*48 + i];
    int rr = bb*32 + r;
    int d = c / 40, tq = c % 40;
    out[((kk*40 + tq)*512 + rr)*2 + d] = acc;
  }
}

extern "C" void kernel_launch(void* const* d_in, const int* in_sizes, int n_in,
                              void* d_out, int out_size, void* d_ws, size_t ws_size,
                              hipStream_t stream)
{
  const float* hx   = (const float*)d_in[0];
  const float* cl   = (const float*)d_in[1];
  const float* yp   = (const float*)d_in[2];
  const float* img  = (const float*)d_in[3];
  const float* w1   = (const float*)d_in[4];
  const float* b1   = (const float*)d_in[5];
  const float* w2   = (const float*)d_in[6];
  const float* b2   = (const float*)d_in[7];
  const float* vw   = (const float*)d_in[8];
  const float* vb   = (const float*)d_in[9];
  const float* scfw = (const float*)d_in[10];
  const float* scfb = (const float*)d_in[11];
  const float* wih  = (const float*)d_in[12];
  const float* whh  = (const float*)d_in[13];
  const float* bih  = (const float*)d_in[14];
  const float* bhh  = (const float*)d_in[15];
  const float* dyw  = (const float*)d_in[16];
  const float* dyb  = (const float*)d_in[17];
  const float* scw  = (const float*)d_in[18];
  const float* scb  = (const float*)d_in[19];

  float* ws   = (float*)d_ws;
  float* fm   = ws + OFF_FM;
  float* c1   = ws + OFF_C1;
  float* w2t  = ws + OFF_W2T;
  float* wt9g = ws + OFF_WT9;
  float* wh3g = ws + OFF_WH3;
  float* wgtg = ws + OFF_WGT;
  float* out  = (float*)d_out;
  (void)wh3g;

  hipLaunchKernelGGL(k_prep,  dim3(464),  dim3(256), 0, stream, w2, scfw, wih, whh, w2t, wt9g, wh3g, wgtg);
  hipLaunchKernelGGL(k_conv1, dim3(6400), dim3(256), 0, stream, img, w1, b1, c1);
  hipLaunchKernelGGL(k_conv2, dim3(3200), dim3(256), 0, stream, c1, w2t, b2, fm);
  hipLaunchKernelGGL(k_seq,   dim3(256),  dim3(256), 0, stream,
      yp, cl, fm, wgtg, wt9g, vw, vb, scfb, bih, bhh, scw, scb, dyw, dyb, hx, out);
}

// Round 9
// 4358.505 us; speedup vs baseline: 1.0236x; 1.0236x over previous
//
#include <hip/hip_runtime.h>
#include <math.h>

typedef unsigned char u8;

#define KK 16
#define TT 40
#define BB 16
#define NN 32
#define BN 512
#define KBN 8192

// ws float offsets — total 5,034,752 floats = 20,139,008 bytes (~20.1 MB)
#define OFF_FM   0u          // 16*80*80*32 = 3276800   fm (b,oh,ow,oc)
#define OFF_C1   3276800u    // 16*16*80*80 = 1638400
#define OFF_W2T  4915200u    // 12800   conv2 W as (ic,kh,kw,oc)
#define OFF_WT9  4928000u    // 21312   wt9T[col][148pad]: col=3c+g, Wcat[g*48+c][k2]
#define OFF_WH3  4949312u    // 2496    wh3T[c][52pad]   = whh[(96+c)*48+k2s]
#define OFF_WGT  4951808u    // 82944   wgt[bin][hh][cc] = scfw[cc][bin*48+hh]

__global__ __launch_bounds__(256) void k_prep(const float* conv2_w, const float* scfw,
                                              const float* wih, const float* whh,
                                              float* w2t, float* wt9T, float* wh3T, float* wgt_g){
  int idx = blockIdx.x*256 + threadIdx.x;
  if (idx < 12800) {
    int oc = idx & 31; int rest = idx >> 5;        // rest = ic*25+kh*5+kw
    w2t[idx] = conv2_w[oc*400 + rest];
  }
  int i2 = idx - 12800;
  if (i2 >= 0 && i2 < 21312) {                     // wt9T[col][k2], col=3c+g, o=g*48+c
    int col = i2 / 148, k2 = i2 % 148;
    float v = 0.f;
    if (k2 < 144) {
      int o = (col % 3)*48 + col/3;
      v = (k2 < 96) ? wih[o*96 + k2] : whh[o*48 + (k2 - 96)];
    }
    wt9T[i2] = v;
  }
  int i3 = idx - 34112;
  if (i3 >= 0 && i3 < 2496) {                      // wh3T[c][k2s]
    int c = i3 / 52, k2s = i3 % 52;
    wh3T[i3] = (k2s < 48) ? whh[(96 + c)*48 + k2s] : 0.f;
  }
  int i4 = idx - 36608;
  if (i4 >= 0 && i4 < 82944) {                     // wgt[bin][hh][cc]
    int bin = i4 / 2304, r2 = i4 % 2304;
    int hh = r2 / 48, cc = r2 % 48;
    wgt_g[i4] = scfw[cc*1728 + bin*48 + hh];
  }
}

__global__ __launch_bounds__(256) void k_conv1(const float* img, const float* w1, const float* b1, float* c1){
  int idx = blockIdx.x*256 + threadIdx.x;          // (b,oc,oh,ow) ow fastest
  int ow = idx % 80, t1 = idx / 80;
  int oh = t1 % 80, t2 = t1 / 80;
  int oc = t2 % 16, b = t2 / 16;
  float acc = b1[oc];
  for (int ic = 0; ic < 4; ++ic)
    for (int kh = 0; kh < 5; ++kh) {
      int ih = oh*2 - 2 + kh;
      if (ih < 0 || ih >= 160) continue;
      const float* ip = img + ((b*4 + ic)*160 + ih)*160;
      const float* wp = w1 + ((oc*4 + ic)*5 + kh)*5;
      #pragma unroll
      for (int kw = 0; kw < 5; ++kw) {
        int iw = ow*2 - 2 + kw;
        if (iw >= 0 && iw < 160) acc += ip[iw] * wp[kw];
      }
    }
  c1[idx] = fmaxf(acc, 0.f);
}

__global__ __launch_bounds__(256) void k_conv2(const float* c1, const float* w2t, const float* b2, float* fm){
  int idx = blockIdx.x*256 + threadIdx.x;          // (b,oh,owg,oc) oc fastest, 4 ow per thread
  int oc = idx & 31;
  int t1 = idx >> 5;
  int owg = t1 % 20; int t2 = t1 / 20;
  int oh = t2 % 80; int b = t2 / 80;
  int ow0 = owg*4;
  float acc0=b2[oc],acc1=b2[oc],acc2=b2[oc],acc3=b2[oc];
  for (int ic = 0; ic < 16; ++ic)
    for (int kh = 0; kh < 5; ++kh) {
      int ih = oh - 2 + kh;
      if (ih < 0 || ih >= 80) continue;
      const float* ip = c1 + ((b*16 + ic)*80 + ih)*80;
      float cv[8];
      #pragma unroll
      for (int q = 0; q < 8; ++q) {
        int iw = ow0 - 2 + q;
        cv[q] = (iw >= 0 && iw < 80) ? ip[iw] : 0.f;
      }
      const float* wp = w2t + (ic*25 + kh*5)*32 + oc;
      #pragma unroll
      for (int kw = 0; kw < 5; ++kw) {
        float wv = wp[kw*32];
        acc0 += cv[kw]   * wv;
        acc1 += cv[kw+1] * wv;
        acc2 += cv[kw+2] * wv;
        acc3 += cv[kw+3] * wv;
      }
    }
  float* op = fm + ((b*80 + oh)*80 + ow0)*32 + oc;
  op[0]  = fmaxf(acc0, 0.f);
  op[32] = fmaxf(acc1, 0.f);
  op[64] = fmaxf(acc2, 0.f);
  op[96] = fmaxf(acc3, 0.f);
}

// Persistent recurrence: one block per (kk,bb) panel, 512 threads (8 waves),
// all 40 timesteps in-kernel. X rows 0-31: base panel replica (k=0,
// self-contained); rows 32-63: own panel. No cross-block deps.
__global__ __launch_bounds__(512) void k_seq(
    const float* __restrict__ y_path, const float* __restrict__ cur_loc,
    const float* __restrict__ fm, const float* __restrict__ wgt,
    const float* __restrict__ wtg,
    const float* __restrict__ vw, const float* __restrict__ vb2,
    const float* __restrict__ scfb, const float* __restrict__ bih,
    const float* __restrict__ bhh, const float* __restrict__ scw,
    const float* __restrict__ scb, const float* __restrict__ dyw,
    const float* __restrict__ dyb, const float* __restrict__ hx,
    float* __restrict__ out)
{
  __align__(16) __shared__ float wts[23808];   // [0,21312) wt9T, [21312,23808) wh3T
  __align__(16) __shared__ float X[64][148];   // [0..95]=x, [96..143]=h, pad 144..147
  __shared__ float PX[2][32], PY[2][32];       // [0]=base(k=0), [1]=own(k=kk)
  __shared__ u8 BINM[2][32][32];
  __shared__ int PLE[2048];                    // (bin<<16)|(cnt<<11)|(jf<<5)|q
  __shared__ float SROW[32];
  __shared__ float SV[432];                    // 0:vw 32:vb 48:scfb 96:bih 240:bhh 384:scw
  __shared__ int lcnt;

  int tid = threadIdx.x;
  int kk = blockIdx.x >> 4;
  int bb = blockIdx.x & 15;

  // ---- one-time staging
  {
    const float4* src = reinterpret_cast<const float4*>(wtg);  // wt9T+wh3T contiguous
    float4* dst = reinterpret_cast<float4*>(wts);
    for (int i = tid; i < 5952; i += 512) dst[i] = src[i];
  }
  for (int i = tid; i < 432; i += 512) {
    float v;
    if (i < 32) v = vw[i];
    else if (i < 48) v = vb2[i-32];
    else if (i < 96) v = scfb[i-48];
    else if (i < 240) v = bih[i-96];
    else if (i < 384) v = bhh[i-240];
    else v = scw[i-384];
    SV[i] = v;
  }
  for (int i = tid; i < 64*48; i += 512) {
    int r = i/48, c = i%48;
    X[r][96+c] = hx[(bb*32 + (r & 31))*48 + c];
  }
  if (tid < 32) SROW[tid] = 0.f;

  int tx = tid & 15, ty = tid >> 4;   // ty 0..31
  int r0 = ty*2;
  float sacc[2] = {0.f, 0.f};
  const float4* Wv = reinterpret_cast<const float4*>(wts);
  const float4* Xv = reinterpret_cast<const float4*>(&X[0][0]);

  for (int t = 0; t < TT; ++t) {
    __syncthreads();
    // ---- positions for both panels
    if (tid < 64) {
      int p = tid >> 5, j = tid & 31;
      int kid = p ? kk : 0;
      PX[p][j] = y_path[((kid*TT + t)*BN + bb*32 + j)*2];
      PY[p][j] = y_path[((kid*TT + t)*BN + bb*32 + j)*2 + 1];
    }
    if (tid == 0) lcnt = 0;
    __syncthreads();

    // ---- pair bins for both panels (c = other(q) - agent(j))
    for (int it2 = 0; it2 < 4; ++it2) {
      int idx = tid + it2*512;               // 2*32*32
      int p = idx >> 10, rem = idx & 1023;
      int j = rem >> 5, q = rem & 31;
      float dx = PX[p][q] - PX[p][j], dy = PY[p][q] - PY[p][j];
      float dist = sqrtf(dx*dx + dy*dy);
      int bin = 255;
      if (q != j && dist >= 0.5f && dist <= 4.0f) {
        float ct = fminf(1.f, fmaxf(-1.f, dx / dist));
        float costh = acosf(ct);
        float theta = (dy < -0.01f) ? (6.28318530717958647692f - costh) : costh;
        int ub = (int)((dist - 0.5f) / 0.58333331346511840820f);
        ub = min(max(ub, 0), 5);
        int vb = (int)(theta / 1.04719758033752441406f);
        vb = min(max(vb, 0), 5);
        bin = ub*6 + vb;
      }
      BINM[p][j][q] = (u8)bin;
    }
    __syncthreads();

    // ---- compact pair list + assemble X cols 0..95
    for (int it2 = 0; it2 < 4; ++it2) {
      int idx = tid + it2*512;
      int p = idx >> 10, rem = idx & 1023;
      int j = rem >> 5, q = rem & 31;
      int bq = BINM[p][j][q];
      if (bq != 255) {
        int cnt2 = 0;
        #pragma unroll
        for (int q2 = 0; q2 < 32; ++q2) cnt2 += (BINM[p][j][q2] == bq) ? 1 : 0;
        int idx2 = atomicAdd(&lcnt, 1);
        PLE[idx2] = (bq << 16) | (cnt2 << 11) | ((p*32 + j) << 5) | q;
      }
    }
    for (int it2 = 0; it2 < 12; ++it2) {
      int task = tid + it2*512;              // 64*96
      int r = task / 96, c = task % 96;
      int p = r >> 5, j = r & 31;
      float val;
      if (c < 32) {
        int u = min(max(40 - (int)PY[p][j], 0), 79);
        int v = min(max((int)PX[p][j], 0), 79);
        val = fm[((bb*80 + u)*80 + v)*32 + c];
      } else if (c < 48) {
        int o = c - 32;
        int rr = bb*32 + j;
        float qx, qy;
        if (t == 0) { qx = cur_loc[rr*2]; qy = cur_loc[rr*2 + 1]; }
        else {
          int kid = p ? kk : 0;
          qx = y_path[((kid*TT + t - 1)*BN + rr)*2];
          qy = y_path[((kid*TT + t - 1)*BN + rr)*2 + 1];
        }
        float vx = (PX[p][j] - qx)*10.f, vy = (PY[p][j] - qy)*10.f;
        val = vx*SV[o*2] + vy*SV[o*2 + 1] + SV[32 + o];
      } else {
        val = SV[c];                          // scfb[c-48]
      }
      X[r][c] = val;
    }
    __syncthreads();

    // ---- sparse social pooling: X[jf][48+lane] += (1/cnt) * (Hbase[q] @ Wblock[bin])
    {
      int P = lcnt;
      int wid = tid >> 6, lane = tid & 63;
      if (lane < 48) {
        for (int p2 = wid; p2 < P; p2 += 8) {
          int e = PLE[p2];
          int bin = e >> 16, cnt2 = (e >> 11) & 31, jf = (e >> 5) & 63, q = e & 31;
          float wv = 1.0f / (float)cnt2;
          const float* wp = wgt + bin*2304 + lane;
          float acc = 0.f;
          #pragma unroll
          for (int hh = 0; hh < 48; ++hh) acc += X[q][96+hh] * wp[hh*48];
          atomicAdd(&X[jf][48 + lane], wv * acc);
        }
      }
    }
    __syncthreads();

    // ---- GRU GEMM: thread owns 2 rows x 9 cols (cols 9tx..9tx+8 of [c][g] layout)
    float a9[2][9], a3[2][3];
    #pragma unroll
    for (int ri = 0; ri < 2; ++ri) {
      #pragma unroll
      for (int m = 0; m < 9; ++m) a9[ri][m] = 0.f;
      #pragma unroll
      for (int m = 0; m < 3; ++m) a3[ri][m] = 0.f;
    }
    {
      int wbase = 333*tx;                     // (9tx)*37
      int xb0 = r0*37, xb1 = xb0 + 37;
      for (int k4 = 0; k4 < 36; ++k4) {
        float4 x0 = Xv[xb0 + k4];
        float4 x1 = Xv[xb1 + k4];
        #pragma unroll
        for (int m = 0; m < 9; ++m) {
          float4 w = Wv[wbase + m*37 + k4];
          a9[0][m] += x0.x*w.x + x0.y*w.y + x0.z*w.z + x0.w*w.w;
          a9[1][m] += x1.x*w.x + x1.y*w.y + x1.z*w.z + x1.w*w.w;
        }
      }
      int hbase = 5328 + 39*tx;               // (21312 + 3tx*52)/4
      for (int k4 = 0; k4 < 12; ++k4) {
        float4 x0 = Xv[xb0 + 24 + k4];        // cols 96..143
        float4 x1 = Xv[xb1 + 24 + k4];
        #pragma unroll
        for (int m = 0; m < 3; ++m) {
          float4 w = Wv[hbase + m*13 + k4];
          a3[0][m] += x0.x*w.x + x0.y*w.y + x0.z*w.z + x0.w*w.w;
          a3[1][m] += x1.x*w.x + x1.y*w.y + x1.z*w.z + x1.w*w.w;
        }
      }
    }
    float hn[2][3];
    #pragma unroll
    for (int ri = 0; ri < 2; ++ri)
      #pragma unroll
      for (int c3 = 0; c3 < 3; ++c3) {
        int c = 3*tx + c3;
        float gR = a9[ri][3*c3+0] + SV[96+c]     + SV[240+c];
        float gZ = a9[ri][3*c3+1] + SV[96+48+c]  + SV[240+48+c];
        float gN = a9[ri][3*c3+2] + SV[96+96+c]  + SV[240+96+c];
        float g3 = a3[ri][c3] + SV[240+96+c];
        float rg = 1.f/(1.f + expf(-gR));
        float zg = 1.f/(1.f + expf(-gZ));
        float nn2 = tanhf(gN + (rg - 1.f)*g3);
        float hold = X[r0+ri][96+c];
        hn[ri][c3] = (1.f - zg)*nn2 + zg*hold;
      }
    __syncthreads();   // all reads of old h complete before overwrite

    // ---- commit h + score partial (register-accumulated)
    #pragma unroll
    for (int ri = 0; ri < 2; ++ri) {
      float sp = 0.f;
      #pragma unroll
      for (int c3 = 0; c3 < 3; ++c3) {
        int c = 3*tx + c3;
        X[r0+ri][96+c] = hn[ri][c3];
        sp += hn[ri][c3]*SV[384+c];
      }
      sacc[ri] += sp;
    }
  }
  // flush per-thread score partials (own panel = rows 32-63 → ty >= 16)
  if (ty >= 16) {
    atomicAdd(&SROW[r0 - 32], sacc[0]);
    atomicAdd(&SROW[r0 - 31], sacc[1]);
  }
  __syncthreads();

  // ---- epilogue: score + delta_y from own rows (32-63)
  if (tid < 32) out[KBN*80 + kk*512 + bb*32 + tid] = SROW[tid] + (float)TT * scb[0];
  for (int it2 = 0; it2 < 5; ++it2) {
    int task = tid + it2*512;                // 32*80
    int r = task / 80, c = task % 80;
    float acc = dyb[c];
    #pragma unroll
    for (int i = 0; i < 48; ++i) acc += X[32+r][96+i] * dyw[c*48 + i];
    int rr = bb*32 + r;
    int d = c / 40, tq = c % 40;
    out[((kk*40 + tq)*512 + rr)*2 + d] = acc;
  }
}

extern "C" void kernel_launch(void* const* d_in, const int* in_sizes, int n_in,
                              void* d_out, int out_size, void* d_ws, size_t ws_size,
                              hipStream_t stream)
{
  const float* hx   = (const float*)d_in[0];
  const float* cl   = (const float*)d_in[1];
  const float* yp   = (const float*)d_in[2];
  const float* img  = (const float*)d_in[3];
  const float* w1   = (const float*)d_in[4];
  const float* b1   = (const float*)d_in[5];
  const float* w2   = (const float*)d_in[6];
  const float* b2   = (const float*)d_in[7];
  const float* vw   = (const float*)d_in[8];
  const float* vb   = (const float*)d_in[9];
  const float* scfw = (const float*)d_in[10];
  const float* scfb = (const float*)d_in[11];
  const float* wih  = (const float*)d_in[12];
  const float* whh  = (const float*)d_in[13];
  const float* bih  = (const float*)d_in[14];
  const float* bhh  = (const float*)d_in[15];
  const float* dyw  = (const float*)d_in[16];
  const float* dyb  = (const float*)d_in[17];
  const float* scw  = (const float*)d_in[18];
  const float* scb  = (const float*)d_in[19];

  float* ws   = (float*)d_ws;
  float* fm   = ws + OFF_FM;
  float* c1   = ws + OFF_C1;
  float* w2t  = ws + OFF_W2T;
  float* wt9T = ws + OFF_WT9;
  float* wh3T = ws + OFF_WH3;
  float* wgtg = ws + OFF_WGT;
  float* out  = (float*)d_out;
  (void)wh3T;

  hipLaunchKernelGGL(k_prep,  dim3(467),  dim3(256), 0, stream, w2, scfw, wih, whh, w2t, wt9T, wh3T, wgtg);
  hipLaunchKernelGGL(k_conv1, dim3(6400), dim3(256), 0, stream, img, w1, b1, c1);
  hipLaunchKernelGGL(k_conv2, dim3(3200), dim3(256), 0, stream, c1, w2t, b2, fm);
  hipLaunchKernelGGL(k_seq,   dim3(256),  dim3(512), 0, stream,
      yp, cl, fm, wgtg, wt9T, vw, vb, scfb, bih, bhh, scw, scb, dyw, dyb, hx, out);
}